// Round 8
// baseline (649.475 us; speedup 1.0000x reference)
//
#include <hip/hip_runtime.h>
#include <math.h>

// Problem constants (fixed by setup_inputs in the reference)
#define IN   128
#define HID  256
#define OUT  64
#define N0   400000
#define N1T  40000
#define N2T  4000
#define E1   640000
#define E2   64000

// ---------------------------------------------------------------------------
// hist: count in-degree of every target node for both edge sets.
// ---------------------------------------------------------------------------
__global__ __launch_bounds__(256) void hist_kernel(
    const int* __restrict__ dst1, const int* __restrict__ dst2,
    int* __restrict__ cnt1, int* __restrict__ cnt2)
{
    int e = blockIdx.x * 256 + threadIdx.x;
    if (e < E1) {
        atomicAdd(&cnt1[dst1[e]], 1);
    } else if (e < E1 + E2) {
        atomicAdd(&cnt2[dst2[e - E1]], 1);
    }
}

// ---------------------------------------------------------------------------
// scan2: both exclusive scans in one launch. block 0 -> set 1, block 1 -> set 2.
// ---------------------------------------------------------------------------
__global__ __launch_bounds__(1024) void scan2_kernel(
    const int* __restrict__ cnt1, int* __restrict__ off1, int* __restrict__ cur1,
    const int* __restrict__ cnt2, int* __restrict__ off2, int* __restrict__ cur2)
{
    const int* cnt; int* off; int* cur; int n;
    if (blockIdx.x == 0) { cnt = cnt1; off = off1; cur = cur1; n = N1T; }
    else                 { cnt = cnt2; off = off2; cur = cur2; n = N2T; }

    __shared__ int sums[1024];
    const int t = threadIdx.x;
    const int chunk = (n + 1023) >> 10;
    const int begin = min(t * chunk, n);
    const int end = min(begin + chunk, n);

    int s = 0;
    for (int i = begin; i < end; ++i) s += cnt[i];
    sums[t] = s;
    __syncthreads();

    for (int d = 1; d < 1024; d <<= 1) {
        int tmp = (t >= d) ? sums[t - d] : 0;
        __syncthreads();
        sums[t] += tmp;
        __syncthreads();
    }

    int run = sums[t] - s;  // exclusive prefix at chunk start
    for (int i = begin; i < end; ++i) {
        off[i] = run;
        cur[i] = run;
        run += cnt[i];
    }
    if (end == n && begin < end) off[n] = run;
}

// ---------------------------------------------------------------------------
// scatter_idx: bucket edges by dst (CSR build). Order within bucket is
// nondeterministic (atomic cursor) — only affects fp summation order.
// ---------------------------------------------------------------------------
__global__ __launch_bounds__(256) void scatter_idx_kernel(
    const int* __restrict__ src1, const int* __restrict__ dst1,
    const int* __restrict__ src2, const int* __restrict__ dst2,
    int* __restrict__ cur1, int* __restrict__ cur2,
    int* __restrict__ ss1, int* __restrict__ ss2)
{
    int e = blockIdx.x * 256 + threadIdx.x;
    if (e < E1) {
        int pos = atomicAdd(&cur1[dst1[e]], 1);
        ss1[pos] = src1[e];
    } else if (e < E1 + E2) {
        int ee = e - E1;
        int pos = atomicAdd(&cur2[dst2[ee]], 1);
        ss2[pos] = src2[ee];
    }
}

// ---------------------------------------------------------------------------
// layer1_fused: gather(mean of x[ss]) -> LDS (transposed) -> register-tiled GEMM.
// C[40000x256] = [agg | x] @ [w_l1; w_r1] + b, relu.
// BM=64, BN=256 (full), K=256. A_s[k][m] stride 68 (16B-aligned float4 rows,
// transposed-write conflicts 32->16-way; GEMM reads are wave-broadcast).
// Gather: wave w owns rows w*16..w*16+15; shfl-broadcast index prefetch,
// 4x unrolled independent row loads, 64 lanes x float2 = 128 cols.
// ---------------------------------------------------------------------------
__global__ __launch_bounds__(256) void layer1_fused_kernel(
    const float* __restrict__ x,
    const int* __restrict__ off, const int* __restrict__ ss,
    const float* __restrict__ w_l, const float* __restrict__ b_l,
    const float* __restrict__ w_r, float* __restrict__ h)
{
    __shared__ __align__(16) float A_s[256][68];  // [k][m]; k<128: agg, k>=128: x
    const int r0 = blockIdx.x * 64;
    const int tid = threadIdx.x;
    const int lane = tid & 63;
    const int wv = tid >> 6;

    // stage x rows 0..63 (transposed) into k = 128..255
    for (int i = tid; i < 64 * 32; i += 256) {
        int r = i >> 5;      // 0..63
        int c4 = i & 31;     // float4 index within 128-float row
        float4 vx = reinterpret_cast<const float4*>(x + (size_t)(r0 + r) * IN)[c4];
        int k = 128 + c4 * 4;
        A_s[k + 0][r] = vx.x; A_s[k + 1][r] = vx.y;
        A_s[k + 2][r] = vx.z; A_s[k + 3][r] = vx.w;
    }

    // gather phase: wave wv handles 16 rows
    for (int i = 0; i < 16; ++i) {
        int r = wv * 16 + i;
        int row = r0 + r;
        int b = off[row], en = off[row + 1];

        float2 acc = make_float2(0.0f, 0.0f);
        for (int base = b; base < en; base += 64) {
            int cnt = min(64, en - base);
            int myidx = (lane < cnt) ? ss[base + lane] : 0;
            int e = 0;
            for (; e + 4 <= cnt; e += 4) {
                int s0 = __shfl(myidx, e);
                int s1 = __shfl(myidx, e + 1);
                int s2 = __shfl(myidx, e + 2);
                int s3 = __shfl(myidx, e + 3);
                float2 v0 = reinterpret_cast<const float2*>(x + (size_t)s0 * IN)[lane];
                float2 v1 = reinterpret_cast<const float2*>(x + (size_t)s1 * IN)[lane];
                float2 v2 = reinterpret_cast<const float2*>(x + (size_t)s2 * IN)[lane];
                float2 v3 = reinterpret_cast<const float2*>(x + (size_t)s3 * IN)[lane];
                acc.x += v0.x + v1.x + v2.x + v3.x;
                acc.y += v0.y + v1.y + v2.y + v3.y;
            }
            for (; e < cnt; ++e) {
                int s = __shfl(myidx, e);
                float2 v = reinterpret_cast<const float2*>(x + (size_t)s * IN)[lane];
                acc.x += v.x;
                acc.y += v.y;
            }
        }
        float inv = 1.0f / fmaxf((float)(en - b), 1.0f);
        A_s[2 * lane][r]     = acc.x * inv;
        A_s[2 * lane + 1][r] = acc.y * inv;
    }
    __syncthreads();

    const int ngrp = tid & 63;   // cols ngrp*4 .. ngrp*4+3
    const int mgrp = tid >> 6;   // rows mgrp*16 .. mgrp*16+15

    float acc[16][4];
#pragma unroll
    for (int m = 0; m < 16; ++m)
#pragma unroll
        for (int j = 0; j < 4; ++j) acc[m][j] = 0.0f;

    const float4* wl4 = reinterpret_cast<const float4*>(w_l);
    const float4* wr4 = reinterpret_cast<const float4*>(w_r);

#pragma unroll 4
    for (int k = 0; k < 128; ++k) {
        float4 w = wl4[k * 64 + ngrp];
        const float4* ap = reinterpret_cast<const float4*>(&A_s[k][mgrp * 16]);
        float4 a0 = ap[0], a1 = ap[1], a2 = ap[2], a3 = ap[3];
        float am[16] = {a0.x, a0.y, a0.z, a0.w, a1.x, a1.y, a1.z, a1.w,
                        a2.x, a2.y, a2.z, a2.w, a3.x, a3.y, a3.z, a3.w};
#pragma unroll
        for (int m = 0; m < 16; ++m) {
            acc[m][0] += am[m] * w.x;
            acc[m][1] += am[m] * w.y;
            acc[m][2] += am[m] * w.z;
            acc[m][3] += am[m] * w.w;
        }
    }
#pragma unroll 4
    for (int k = 0; k < 128; ++k) {
        float4 w = wr4[k * 64 + ngrp];
        const float4* ap = reinterpret_cast<const float4*>(&A_s[128 + k][mgrp * 16]);
        float4 a0 = ap[0], a1 = ap[1], a2 = ap[2], a3 = ap[3];
        float am[16] = {a0.x, a0.y, a0.z, a0.w, a1.x, a1.y, a1.z, a1.w,
                        a2.x, a2.y, a2.z, a2.w, a3.x, a3.y, a3.z, a3.w};
#pragma unroll
        for (int m = 0; m < 16; ++m) {
            acc[m][0] += am[m] * w.x;
            acc[m][1] += am[m] * w.y;
            acc[m][2] += am[m] * w.z;
            acc[m][3] += am[m] * w.w;
        }
    }

    float4 b = reinterpret_cast<const float4*>(b_l)[ngrp];
#pragma unroll
    for (int m = 0; m < 16; ++m) {
        float4 o;
        o.x = fmaxf(acc[m][0] + b.x, 0.0f);
        o.y = fmaxf(acc[m][1] + b.y, 0.0f);
        o.z = fmaxf(acc[m][2] + b.z, 0.0f);
        o.w = fmaxf(acc[m][3] + b.w, 0.0f);
        reinterpret_cast<float4*>(h + (size_t)(r0 + mgrp * 16 + m) * HID)[ngrp] = o;
    }
}

// ---------------------------------------------------------------------------
// layer2_fused: per output row (one wave): gather(mean of h[ss]) -> LDS,
// stage root h[i] -> LDS, GEMM 256->64, wave-wide log_softmax.
// ---------------------------------------------------------------------------
__global__ __launch_bounds__(64) void layer2_fused_kernel(
    const float* __restrict__ hsrc,
    const int* __restrict__ off, const int* __restrict__ ss,
    const float* __restrict__ w_l, const float* __restrict__ b_l,
    const float* __restrict__ w_r, float* __restrict__ out)
{
    __shared__ __align__(16) float a_s[HID];
    __shared__ __align__(16) float h_s[HID];
    const int i = blockIdx.x;
    const int j = threadIdx.x;  // 0..63

    // stage root row
    reinterpret_cast<float4*>(h_s)[j] =
        reinterpret_cast<const float4*>(hsrc + (size_t)i * HID)[j];

    // gather neighbors (64 lanes x float4 = 256 cols)
    int b = off[i], en = off[i + 1];
    float4 acc4 = make_float4(0.0f, 0.0f, 0.0f, 0.0f);
    for (int base = b; base < en; base += 64) {
        int cnt = min(64, en - base);
        int myidx = (j < cnt) ? ss[base + j] : 0;
        int e = 0;
        for (; e + 2 <= cnt; e += 2) {
            int s0 = __shfl(myidx, e);
            int s1 = __shfl(myidx, e + 1);
            float4 v0 = reinterpret_cast<const float4*>(hsrc + (size_t)s0 * HID)[j];
            float4 v1 = reinterpret_cast<const float4*>(hsrc + (size_t)s1 * HID)[j];
            acc4.x += v0.x + v1.x; acc4.y += v0.y + v1.y;
            acc4.z += v0.z + v1.z; acc4.w += v0.w + v1.w;
        }
        for (; e < cnt; ++e) {
            int s = __shfl(myidx, e);
            float4 v = reinterpret_cast<const float4*>(hsrc + (size_t)s * HID)[j];
            acc4.x += v.x; acc4.y += v.y; acc4.z += v.z; acc4.w += v.w;
        }
    }
    float inv = 1.0f / fmaxf((float)(en - b), 1.0f);
    acc4.x *= inv; acc4.y *= inv; acc4.z *= inv; acc4.w *= inv;
    reinterpret_cast<float4*>(a_s)[j] = acc4;
    __syncthreads();

    float acc = b_l[j];
    for (int k = 0; k < HID; ++k) {
        acc += a_s[k] * w_l[k * OUT + j] + h_s[k] * w_r[k * OUT + j];
    }

    // wave-wide (64-lane) log_softmax
    float m = acc;
#pragma unroll
    for (int off2 = 32; off2; off2 >>= 1) m = fmaxf(m, __shfl_xor(m, off2));
    float ex = expf(acc - m);
#pragma unroll
    for (int off2 = 32; off2; off2 >>= 1) ex += __shfl_xor(ex, off2);
    out[(size_t)i * OUT + j] = acc - m - logf(ex);
}

// ---------------------------------------------------------------------------
extern "C" void kernel_launch(void* const* d_in, const int* in_sizes, int n_in,
                              void* d_out, int out_size, void* d_ws, size_t ws_size,
                              hipStream_t stream)
{
    const float* x    = (const float*)d_in[0];
    const int*   src1 = (const int*)  d_in[1];
    const int*   dst1 = (const int*)  d_in[2];
    const int*   src2 = (const int*)  d_in[3];
    const int*   dst2 = (const int*)  d_in[4];
    const float* w_l1 = (const float*)d_in[5];
    const float* b_l1 = (const float*)d_in[6];
    const float* w_r1 = (const float*)d_in[7];
    const float* w_l2 = (const float*)d_in[8];
    const float* b_l2 = (const float*)d_in[9];
    const float* w_r2 = (const float*)d_in[10];
    float* out = (float*)d_out;

    // Workspace layout:
    // ints:  [cnt1:N1T | cnt2:N2T | off1:N1T+1 | off2:N2T+1 | cur1:N1T | cur2:N2T | ss1:E1 | ss2:E2]
    // floats:[h:N1T*HID]
    int* ws_i = (int*)d_ws;
    int* cnt1 = ws_i;
    int* cnt2 = cnt1 + N1T;
    int* off1 = cnt2 + N2T;
    int* off2 = off1 + N1T + 1;
    int* cur1 = off2 + N2T + 1;
    int* cur2 = cur1 + N1T;
    int* ss1  = cur2 + N2T;
    int* ss2  = ss1 + E1;
    float* h  = (float*)(ss2 + E2);

    // zero only the histogram counters
    hipMemsetAsync(cnt1, 0, (N1T + N2T) * sizeof(int), stream);

    const int ET = E1 + E2;
    hist_kernel<<<(ET + 255) / 256, 256, 0, stream>>>(dst1, dst2, cnt1, cnt2);
    scan2_kernel<<<2, 1024, 0, stream>>>(cnt1, off1, cur1, cnt2, off2, cur2);
    scatter_idx_kernel<<<(ET + 255) / 256, 256, 0, stream>>>(src1, dst1, src2, dst2,
                                                             cur1, cur2, ss1, ss2);
    layer1_fused_kernel<<<N1T / 64, 256, 0, stream>>>(x, off1, ss1, w_l1, b_l1, w_r1, h);
    layer2_fused_kernel<<<N2T, 64, 0, stream>>>(h, off2, ss2, w_l2, b_l2, w_r2, out);
}